// Round 2
// baseline (475.606 us; speedup 1.0000x reference)
//
#include <hip/hip_runtime.h>
#include <hip/hip_bf16.h>
#include <hip/hip_fp16.h>

#define OUT_F 4096
#define IN_F  4096
#define BATCH 4096
#define RANK  32
#define NPROT 32
#define KPAD  4160   // 4096 + 32 (svd ext) + 32 (zero pad) — multiple of 64

typedef __hip_bfloat16 bf16;
using bf16x8 = __attribute__((ext_vector_type(8))) short;
using f32x4  = __attribute__((ext_vector_type(4))) float;

__device__ __forceinline__ void gload_lds16(const void* g, void* l) {
  __builtin_amdgcn_global_load_lds(
      (const __attribute__((address_space(1))) unsigned int*)g,
      (__attribute__((address_space(3))) unsigned int*)l,
      16, 0, 0);
}

__device__ __forceinline__ unsigned short bf16_bits(float f) {
  bf16 h = __float2bfloat16(f);
  return *(unsigned short*)&h;
}

// ---------------------------------------------------------------------------
// A-prep: xs[b,c] = x[b,c] * scales[c/128]  (bf16), zero the pad cols.
__global__ __launch_bounds__(256) void prep_xs(const float* __restrict__ x,
                                               const float* __restrict__ scales,
                                               bf16* __restrict__ A) {
  int b = blockIdx.x;
  int tid = threadIdx.x;
  const float4* xr = (const float4*)(x + (size_t)b * IN_F);
  bf16* Ar = A + (size_t)b * KPAD;
#pragma unroll
  for (int j = 0; j < 4; ++j) {
    int f = tid + j * 256;               // float4 index in [0,1024)
    float4 xv = xr[f];
    float sv = scales[f >> 5];           // cols 4f..4f+3 share group f>>5
    ushort4 pk = make_ushort4(bf16_bits(xv.x * sv), bf16_bits(xv.y * sv),
                              bf16_bits(xv.z * sv), bf16_bits(xv.w * sv));
    *(ushort4*)(Ar + 4 * (size_t)f) = pk;
  }
  if (tid < 32) {  // zero K pad (cols 4128..4159)
    bf16 z = __float2bfloat16(0.0f);
    Ar[IN_F + RANK + tid] = z;
  }
}

// ---------------------------------------------------------------------------
// T = x @ V, stored as bf16 into A cols 4096..4127 (UNSCALED on both sides).
__global__ __launch_bounds__(256) void prep_t(const float* __restrict__ x,
                                              const float* __restrict__ v,
                                              bf16* __restrict__ A) {
  int tid = threadIdx.x;
  int row = blockIdx.x * 8 + (tid >> 5);
  int r = tid & 31;
  const float* xr = x + (size_t)row * IN_F;
  float acc = 0.f;
#pragma unroll 16
  for (int c = 0; c < IN_F; ++c)
    acc = fmaf(xr[c], v[(size_t)c * RANK + r], acc);
  A[(size_t)row * KPAD + IN_F + r] = __float2bfloat16(acc);
}

// ---------------------------------------------------------------------------
// B-unpack: split-layout nibbles. Each int32 of `packed` holds ONE byte
// (two nibbles). lo nibbles -> rows 0..2047, hi nibbles -> rows 2048..4095.
// Weights (q-8) in [-8,7] are exact in bf16.
__global__ __launch_bounds__(256) void prep_b(const int* __restrict__ packed,
                                              bf16* __restrict__ B) {
  size_t i = (size_t)blockIdx.x * 256 + threadIdx.x;   // [0, 2097152)
  int4 p = ((const int4*)packed)[i];
  size_t e = i * 4;
  int o = (int)(e >> 12);
  int c = (int)(e & 4095);
  int vals[4] = {p.x, p.y, p.z, p.w};
  unsigned short lo[4], hi[4];
#pragma unroll
  for (int j = 0; j < 4; ++j) {
    lo[j] = bf16_bits((float)((vals[j] & 15) - 8));
    hi[j] = bf16_bits((float)(((vals[j] >> 4) & 15) - 8));
  }
  *(ushort4*)(B + (size_t)o * KPAD + c) = make_ushort4(lo[0], lo[1], lo[2], lo[3]);
  *(ushort4*)(B + (size_t)(o + 2048) * KPAD + c) = make_ushort4(hi[0], hi[1], hi[2], hi[3]);
}

// ---------------------------------------------------------------------------
// B ext cols: B[o][4096+j] = U[o][j] for j<32, 0 for pad.
__global__ __launch_bounds__(256) void prep_bext(const float* __restrict__ u,
                                                 bf16* __restrict__ B) {
  int i = blockIdx.x * 256 + threadIdx.x;  // [0, 262144)
  int o = i >> 6, j = i & 63;
  float val = (j < RANK) ? u[o * RANK + j] : 0.f;
  B[(size_t)o * KPAD + IN_F + j] = __float2bfloat16(val);
}

// ---------------------------------------------------------------------------
// Protected rows: A carries x*s, so the protected B row must carry pc/s
// (then (x*s)*(pc/s) = x*pc, matching the reference's unscaled overwrite).
// Ext cols zeroed — protected rows get no SVD term.
__global__ __launch_bounds__(256) void prep_prot(const float* __restrict__ pc,
                                                 const float* __restrict__ scales,
                                                 const int* __restrict__ pidx,
                                                 bf16* __restrict__ B) {
  int bi = blockIdx.x;            // [0, 32)
  int row = pidx[bi];
  bf16* Br = B + (size_t)row * KPAD;
  for (int c = threadIdx.x; c < KPAD; c += 256) {
    float val = (c < IN_F) ? pc[(size_t)bi * IN_F + c] / scales[c >> 7] : 0.f;
    Br[c] = __float2bfloat16(val);
  }
}

// ---------------------------------------------------------------------------
// Main GEMM: out[b,o] = sum_k A[b,k] * B[o,k], K = 4160, both row-major.
// 128x128 tile, BK=64, 4 waves (2x2, each 64x64 = 4x4 frags of 16x16x32 MFMA).
// global_load_lds width 16 with XOR-swizzled LDS (pre-swizzled global source).
__global__ __launch_bounds__(256) void gemm_bt(const bf16* __restrict__ A,
                                               const bf16* __restrict__ B,
                                               float* __restrict__ out) {
  __shared__ bf16 As[128 * 64];
  __shared__ bf16 Bs[128 * 64];

  int bid = blockIdx.x;
  // XCD-aware swizzle: 1024 blocks, 8 XCDs, 128 contiguous per XCD.
  int swz = (bid & 7) * 128 + (bid >> 3);
  int brow = (swz >> 5) << 7;   // batch-row tile base
  int bcol = (swz & 31) << 7;   // out-col (o) tile base

  int tid = threadIdx.x;
  int lane = tid & 63;
  int wave = tid >> 6;
  int wrow = (wave >> 1) << 6;
  int wcol = (wave & 1) << 6;

  f32x4 acc[4][4];
#pragma unroll
  for (int i = 0; i < 4; ++i)
#pragma unroll
    for (int j = 0; j < 4; ++j)
      acc[i][j] = (f32x4){0.f, 0.f, 0.f, 0.f};

  // Staging: idx = call*256+tid covers (row=idx/8, slot=idx%8).
  // LDS dest linear; global source column pre-swizzled: srcslot = slot ^ (row&7).
  const char* gA[4]; const char* gB[4]; char* lA[4]; char* lB[4];
#pragma unroll
  for (int i = 0; i < 4; ++i) {
    int idx = i * 256 + tid;
    int row = idx >> 3, slot = idx & 7;
    int srcslot = slot ^ (row & 7);
    gA[i] = (const char*)(A + (size_t)(brow + row) * KPAD) + srcslot * 16;
    gB[i] = (const char*)(B + (size_t)(bcol + row) * KPAD) + srcslot * 16;
    lA[i] = (char*)As + idx * 16;
    lB[i] = (char*)Bs + idx * 16;
  }

  // Fragment read byte-offsets (swizzled): row r, logical 16B slot sl -> sl^(r&7).
  int aoff[4][2], boff[4][2];
#pragma unroll
  for (int m = 0; m < 4; ++m)
#pragma unroll
    for (int kb = 0; kb < 2; ++kb) {
      int sl = kb * 4 + (lane >> 4);
      int ra = wrow + m * 16 + (lane & 15);
      aoff[m][kb] = ra * 128 + ((sl ^ (ra & 7)) << 4);
      int rb = wcol + m * 16 + (lane & 15);
      boff[m][kb] = rb * 128 + ((sl ^ (rb & 7)) << 4);
    }

  for (int k0 = 0; k0 < KPAD; k0 += 64) {
    size_t kbyte = (size_t)k0 * 2;
#pragma unroll
    for (int i = 0; i < 4; ++i) gload_lds16(gA[i] + kbyte, lA[i]);
#pragma unroll
    for (int i = 0; i < 4; ++i) gload_lds16(gB[i] + kbyte, lB[i]);
    __syncthreads();   // compiler drains vmcnt(0) before s_barrier

#pragma unroll
    for (int kb = 0; kb < 2; ++kb) {
      bf16x8 av[4], bv[4];
#pragma unroll
      for (int m = 0; m < 4; ++m)
        av[m] = *(const bf16x8*)((const char*)As + aoff[m][kb]);
#pragma unroll
      for (int n = 0; n < 4; ++n)
        bv[n] = *(const bf16x8*)((const char*)Bs + boff[n][kb]);
#pragma unroll
      for (int m = 0; m < 4; ++m)
#pragma unroll
        for (int n = 0; n < 4; ++n)
          acc[m][n] = __builtin_amdgcn_mfma_f32_16x16x32_bf16(av[m], bv[n], acc[m][n], 0, 0, 0);
    }
    __syncthreads();   // before next-iter staging overwrites LDS
  }

  // Epilogue: C/D map col=lane&15 (o-dim), row=(lane>>4)*4+reg (batch).
  // Round through fp16 to match the reference's fp16 cast.
#pragma unroll
  for (int m = 0; m < 4; ++m)
#pragma unroll
    for (int n = 0; n < 4; ++n)
#pragma unroll
      for (int r = 0; r < 4; ++r) {
        int mm = brow + wrow + m * 16 + ((lane >> 4) << 2) + r;
        int nn = bcol + wcol + n * 16 + (lane & 15);
        float v = acc[m][n][r];
        out[(size_t)mm * OUT_F + nn] = __half2float(__float2half(v));
      }
}

// ---------------------------------------------------------------------------
extern "C" void kernel_launch(void* const* d_in, const int* in_sizes, int n_in,
                              void* d_out, int out_size, void* d_ws, size_t ws_size,
                              hipStream_t stream) {
  const float* x      = (const float*)d_in[0];
  const int*   packed = (const int*)d_in[1];
  const float* scales = (const float*)d_in[2];
  const float* svd_u  = (const float*)d_in[3];
  const float* svd_v  = (const float*)d_in[4];
  const float* pc     = (const float*)d_in[5];
  const int*   pidx   = (const int*)d_in[6];
  float* out = (float*)d_out;

  bf16* A = (bf16*)d_ws;                       // [BATCH][KPAD] = 34.1 MB
  bf16* B = A + (size_t)BATCH * KPAD;          // [OUT_F][KPAD] = 34.1 MB

  prep_xs  <<<BATCH, 256, 0, stream>>>(x, scales, A);
  prep_t   <<<512,   256, 0, stream>>>(x, svd_v, A);
  prep_b   <<<8192,  256, 0, stream>>>(packed, B);
  prep_bext<<<1024,  256, 0, stream>>>(svd_u, B);
  prep_prot<<<32,    256, 0, stream>>>(pc, scales, pidx, B);
  gemm_bt  <<<1024,  256, 0, stream>>>(A, B, out);
}

// Round 3
// 372.055 us; speedup vs baseline: 1.2783x; 1.2783x over previous
//
#include <hip/hip_runtime.h>
#include <hip/hip_bf16.h>
#include <hip/hip_fp16.h>

#define OUT_F 4096
#define IN_F  4096
#define BATCH 4096
#define RANK  32
#define NPROT 32
#define KPAD  4160   // 4096 + 32 (svd ext) + 32 (zero pad) — multiple of 64

typedef __hip_bfloat16 bf16;
using bf16x8 = __attribute__((ext_vector_type(8))) short;
using f32x4  = __attribute__((ext_vector_type(4))) float;

__device__ __forceinline__ void gload_lds16(const void* g, void* l) {
  __builtin_amdgcn_global_load_lds(
      (const __attribute__((address_space(1))) unsigned int*)g,
      (__attribute__((address_space(3))) unsigned int*)l,
      16, 0, 0);
}

__device__ __forceinline__ unsigned short bf16_bits(float f) {
  bf16 h = __float2bfloat16(f);
  return *(unsigned short*)&h;
}

// ---------------------------------------------------------------------------
// A-prep: xs[b,c] = x[b,c] * scales[c/128]  (bf16), zero the pad cols.
__global__ __launch_bounds__(256) void prep_xs(const float* __restrict__ x,
                                               const float* __restrict__ scales,
                                               bf16* __restrict__ A) {
  int b = blockIdx.x;
  int tid = threadIdx.x;
  const float4* xr = (const float4*)(x + (size_t)b * IN_F);
  bf16* Ar = A + (size_t)b * KPAD;
#pragma unroll
  for (int j = 0; j < 4; ++j) {
    int f = tid + j * 256;               // float4 index in [0,1024)
    float4 xv = xr[f];
    float sv = scales[f >> 5];           // cols 4f..4f+3 share group f>>5
    ushort4 pk = make_ushort4(bf16_bits(xv.x * sv), bf16_bits(xv.y * sv),
                              bf16_bits(xv.z * sv), bf16_bits(xv.w * sv));
    *(ushort4*)(Ar + 4 * (size_t)f) = pk;
  }
  if (tid < 32) {  // zero K pad (cols 4128..4159)
    bf16 z = __float2bfloat16(0.0f);
    Ar[IN_F + RANK + tid] = z;
  }
}

// ---------------------------------------------------------------------------
// Misc small prep: blocks [0,512) build VsT[r][c] = V[c][r]/s[c/128] (bf16);
// blocks [512,1536) write B ext cols: B[o][4096+j] = U[o][j] (j<32), 0 pad.
__global__ __launch_bounds__(256) void prep_misc(const float* __restrict__ v,
                                                 const float* __restrict__ scales,
                                                 const float* __restrict__ u,
                                                 bf16* __restrict__ vst,
                                                 bf16* __restrict__ B) {
  int bid = blockIdx.x;
  if (bid < 512) {
    int gid = bid * 256 + threadIdx.x;       // [0, 131072)
    int c = gid >> 5, r = gid & 31;          // read coalesced over V
    float val = v[(size_t)c * RANK + r] / scales[c >> 7];
    vst[(size_t)r * IN_F + c] = __float2bfloat16(val);
  } else {
    int i = (bid - 512) * 256 + threadIdx.x; // [0, 262144)
    int o = i >> 6, j = i & 63;
    float val = (j < RANK) ? u[o * RANK + j] : 0.f;
    B[(size_t)o * KPAD + IN_F + j] = __float2bfloat16(val);
  }
}

// ---------------------------------------------------------------------------
// T = xs @ VsT^T via MFMA, written as bf16 into A cols 4096..4127.
// (x@V == (x·s) @ (V/s), so the tiny SVD term rides on the bf16 xs.)
// 1 wave/block, 256 blocks; each wave: 16 rows x 32 cols, full K=4096.
// Fragment layout identical to the (verified) gemm_bt: A row = lane&15,
// k = (lane>>4)*8..+8 within each 32-chunk; C/D row=(lane>>4)*4+reg, col=lane&15.
__global__ __launch_bounds__(64) void prep_t_mfma(const bf16* __restrict__ A_ro,
                                                  const bf16* __restrict__ vst,
                                                  bf16* __restrict__ A_wr) {
  int lane = threadIdx.x;
  int row0 = blockIdx.x * 16;
  const bf16* arow  = A_ro + (size_t)(row0 + (lane & 15)) * KPAD + ((lane >> 4) << 3);
  const bf16* brow0 = vst + (size_t)(lane & 15) * IN_F + ((lane >> 4) << 3);
  const bf16* brow1 = vst + (size_t)(16 + (lane & 15)) * IN_F + ((lane >> 4) << 3);
  f32x4 acc0 = (f32x4){0.f, 0.f, 0.f, 0.f};
  f32x4 acc1 = (f32x4){0.f, 0.f, 0.f, 0.f};
#pragma unroll 8
  for (int k0 = 0; k0 < IN_F; k0 += 32) {
    bf16x8 av  = *(const bf16x8*)(arow + k0);
    bf16x8 bv0 = *(const bf16x8*)(brow0 + k0);
    bf16x8 bv1 = *(const bf16x8*)(brow1 + k0);
    acc0 = __builtin_amdgcn_mfma_f32_16x16x32_bf16(av, bv0, acc0, 0, 0, 0);
    acc1 = __builtin_amdgcn_mfma_f32_16x16x32_bf16(av, bv1, acc1, 0, 0, 0);
  }
#pragma unroll
  for (int r = 0; r < 4; ++r) {
    int row = row0 + ((lane >> 4) << 2) + r;
    bf16* Tr = A_wr + (size_t)row * KPAD + IN_F;
    Tr[lane & 15]        = __float2bfloat16(acc0[r]);
    Tr[16 + (lane & 15)] = __float2bfloat16(acc1[r]);
  }
}

// ---------------------------------------------------------------------------
// B-unpack: split-layout nibbles. lo nibbles -> rows 0..2047, hi -> 2048..4095.
__global__ __launch_bounds__(256) void prep_b(const int* __restrict__ packed,
                                              bf16* __restrict__ B) {
  size_t i = (size_t)blockIdx.x * 256 + threadIdx.x;   // [0, 2097152)
  int4 p = ((const int4*)packed)[i];
  size_t e = i * 4;
  int o = (int)(e >> 12);
  int c = (int)(e & 4095);
  int vals[4] = {p.x, p.y, p.z, p.w};
  unsigned short lo[4], hi[4];
#pragma unroll
  for (int j = 0; j < 4; ++j) {
    lo[j] = bf16_bits((float)((vals[j] & 15) - 8));
    hi[j] = bf16_bits((float)(((vals[j] >> 4) & 15) - 8));
  }
  *(ushort4*)(B + (size_t)o * KPAD + c) = make_ushort4(lo[0], lo[1], lo[2], lo[3]);
  *(ushort4*)(B + (size_t)(o + 2048) * KPAD + c) = make_ushort4(hi[0], hi[1], hi[2], hi[3]);
}

// ---------------------------------------------------------------------------
// Protected rows: A carries x*s, so protected B rows carry pc/s; ext cols = 0.
__global__ __launch_bounds__(256) void prep_prot(const float* __restrict__ pc,
                                                 const float* __restrict__ scales,
                                                 const int* __restrict__ pidx,
                                                 bf16* __restrict__ B) {
  int bi = blockIdx.x;            // [0, 32)
  int row = pidx[bi];
  bf16* Br = B + (size_t)row * KPAD;
  for (int c = threadIdx.x; c < KPAD; c += 256) {
    float val = (c < IN_F) ? pc[(size_t)bi * IN_F + c] / scales[c >> 7] : 0.f;
    Br[c] = __float2bfloat16(val);
  }
}

// ---------------------------------------------------------------------------
// Main GEMM: out[b,o] = sum_k A[b,k] * B[o,k], K = 4160, both row-major.
// 128x128 tile, BK=64, 4 waves (2x2, each 64x64 = 4x4 frags of 16x16x32 MFMA).
// global_load_lds width 16 with XOR-swizzled LDS (pre-swizzled global source).
__global__ __launch_bounds__(256) void gemm_bt(const bf16* __restrict__ A,
                                               const bf16* __restrict__ B,
                                               float* __restrict__ out) {
  __shared__ bf16 As[128 * 64];
  __shared__ bf16 Bs[128 * 64];

  int bid = blockIdx.x;
  // XCD-aware swizzle: 1024 blocks, 8 XCDs, 128 contiguous per XCD.
  int swz = (bid & 7) * 128 + (bid >> 3);
  int brow = (swz >> 5) << 7;   // batch-row tile base
  int bcol = (swz & 31) << 7;   // out-col (o) tile base

  int tid = threadIdx.x;
  int lane = tid & 63;
  int wave = tid >> 6;
  int wrow = (wave >> 1) << 6;
  int wcol = (wave & 1) << 6;

  f32x4 acc[4][4];
#pragma unroll
  for (int i = 0; i < 4; ++i)
#pragma unroll
    for (int j = 0; j < 4; ++j)
      acc[i][j] = (f32x4){0.f, 0.f, 0.f, 0.f};

  // Staging: idx = call*256+tid covers (row=idx/8, slot=idx%8).
  // LDS dest linear; global source column pre-swizzled: srcslot = slot ^ (row&7).
  const char* gA[4]; const char* gB[4]; char* lA[4]; char* lB[4];
#pragma unroll
  for (int i = 0; i < 4; ++i) {
    int idx = i * 256 + tid;
    int row = idx >> 3, slot = idx & 7;
    int srcslot = slot ^ (row & 7);
    gA[i] = (const char*)(A + (size_t)(brow + row) * KPAD) + srcslot * 16;
    gB[i] = (const char*)(B + (size_t)(bcol + row) * KPAD) + srcslot * 16;
    lA[i] = (char*)As + idx * 16;
    lB[i] = (char*)Bs + idx * 16;
  }

  // Fragment read byte-offsets (swizzled): row r, logical 16B slot sl -> sl^(r&7).
  int aoff[4][2], boff[4][2];
#pragma unroll
  for (int m = 0; m < 4; ++m)
#pragma unroll
    for (int kb = 0; kb < 2; ++kb) {
      int sl = kb * 4 + (lane >> 4);
      int ra = wrow + m * 16 + (lane & 15);
      aoff[m][kb] = ra * 128 + ((sl ^ (ra & 7)) << 4);
      int rb = wcol + m * 16 + (lane & 15);
      boff[m][kb] = rb * 128 + ((sl ^ (rb & 7)) << 4);
    }

  for (int k0 = 0; k0 < KPAD; k0 += 64) {
    size_t kbyte = (size_t)k0 * 2;
#pragma unroll
    for (int i = 0; i < 4; ++i) gload_lds16(gA[i] + kbyte, lA[i]);
#pragma unroll
    for (int i = 0; i < 4; ++i) gload_lds16(gB[i] + kbyte, lB[i]);
    __syncthreads();   // compiler drains vmcnt(0) before s_barrier

#pragma unroll
    for (int kb = 0; kb < 2; ++kb) {
      bf16x8 av[4], bv[4];
#pragma unroll
      for (int m = 0; m < 4; ++m)
        av[m] = *(const bf16x8*)((const char*)As + aoff[m][kb]);
#pragma unroll
      for (int n = 0; n < 4; ++n)
        bv[n] = *(const bf16x8*)((const char*)Bs + boff[n][kb]);
#pragma unroll
      for (int m = 0; m < 4; ++m)
#pragma unroll
        for (int n = 0; n < 4; ++n)
          acc[m][n] = __builtin_amdgcn_mfma_f32_16x16x32_bf16(av[m], bv[n], acc[m][n], 0, 0, 0);
    }
    __syncthreads();   // before next-iter staging overwrites LDS
  }

  // Epilogue: C/D map col=lane&15 (o-dim), row=(lane>>4)*4+reg (batch).
  // Round through fp16 to match the reference's fp16 cast.
#pragma unroll
  for (int m = 0; m < 4; ++m)
#pragma unroll
    for (int n = 0; n < 4; ++n)
#pragma unroll
      for (int r = 0; r < 4; ++r) {
        int mm = brow + wrow + m * 16 + ((lane >> 4) << 2) + r;
        int nn = bcol + wcol + n * 16 + (lane & 15);
        float v = acc[m][n][r];
        out[(size_t)mm * OUT_F + nn] = __half2float(__float2half(v));
      }
}

// ---------------------------------------------------------------------------
extern "C" void kernel_launch(void* const* d_in, const int* in_sizes, int n_in,
                              void* d_out, int out_size, void* d_ws, size_t ws_size,
                              hipStream_t stream) {
  const float* x      = (const float*)d_in[0];
  const int*   packed = (const int*)d_in[1];
  const float* scales = (const float*)d_in[2];
  const float* svd_u  = (const float*)d_in[3];
  const float* svd_v  = (const float*)d_in[4];
  const float* pc     = (const float*)d_in[5];
  const int*   pidx   = (const int*)d_in[6];
  float* out = (float*)d_out;

  bf16* A   = (bf16*)d_ws;                     // [BATCH][KPAD] = 34.1 MB
  bf16* B   = A + (size_t)BATCH * KPAD;        // [OUT_F][KPAD] = 34.1 MB
  bf16* vst = B + (size_t)OUT_F * KPAD;        // [RANK][IN_F]  = 0.25 MB

  prep_xs    <<<BATCH, 256, 0, stream>>>(x, scales, A);
  prep_misc  <<<1536,  256, 0, stream>>>(svd_v, scales, svd_u, vst, B);
  prep_t_mfma<<<256,   64,  0, stream>>>(A, vst, A);
  prep_b     <<<8192,  256, 0, stream>>>(packed, B);
  prep_prot  <<<32,    256, 0, stream>>>(pc, scales, pidx, B);
  gemm_bt    <<<1024,  256, 0, stream>>>(A, B, out);
}